// Round 1
// baseline (168.850 us; speedup 1.0000x reference)
//
#include <hip/hip_runtime.h>

// ExpertLoRA: N=8192, Z=1024, H=2048, W=64, R=8, SCALE=1.0
// out = out_pre + ((silu(h_pre + (z·a1[e]^T)·b1[e]^T)) · a2[e]^T) · b2[e]^T
// One block per token; 256 threads; all-f32 math.

constexpr int Zd = 1024;
constexpr int Hd = 2048;
constexpr int Rr = 8;
constexpr float kScale = 1.0f;

__global__ __launch_bounds__(256) void expert_lora_kernel(
    const float* __restrict__ z,        // [N, Z]
    const int*   __restrict__ a_idx,    // [N]
    const float* __restrict__ h_pre,    // [N, H]
    const float* __restrict__ out_pre,  // [N, Z]
    const float* __restrict__ a1,       // [W, R, Z]
    const float* __restrict__ b1,       // [W, H, R]
    const float* __restrict__ a2,       // [W, R, H]
    const float* __restrict__ b2,       // [W, Z, R]
    float* __restrict__ out)            // [N, Z]
{
    const int n    = blockIdx.x;
    const int t    = threadIdx.x;
    const int wave = t >> 6;
    const int lane = t & 63;
    const int e    = a_idx[n];

    __shared__ float red[Rr][4];
    __shared__ float t1s[Rr];
    __shared__ float t2s[Rr];

    // ---------- Phase 1: t1[r] = sum_d z[n,d] * a1[e,r,d] ----------
    const float* __restrict__ zrow = z  + (size_t)n * Zd;
    const float* __restrict__ a1e  = a1 + (size_t)e * (Rr * Zd);

    float p[Rr];
#pragma unroll
    for (int r = 0; r < Rr; ++r) p[r] = 0.f;

#pragma unroll
    for (int i = 0; i < Zd / 256; ++i) {
        const int d = t + i * 256;
        const float zv = zrow[d];
#pragma unroll
        for (int r = 0; r < Rr; ++r)
            p[r] = fmaf(zv, a1e[r * Zd + d], p[r]);
    }
#pragma unroll
    for (int r = 0; r < Rr; ++r) {
        float v = p[r];
#pragma unroll
        for (int off = 32; off > 0; off >>= 1)
            v += __shfl_down(v, off, 64);
        if (lane == 0) red[r][wave] = v;
    }
    __syncthreads();
    if (t < Rr)
        t1s[t] = red[t][0] + red[t][1] + red[t][2] + red[t][3];
    __syncthreads();

    float t1l[Rr];
#pragma unroll
    for (int r = 0; r < Rr; ++r) t1l[r] = t1s[r];

    // ---------- Phase 2: h = silu(h_pre + t1·b1^T); t2[r] = sum_h h * a2[e,r,h] ----------
    const float* __restrict__ hrow = h_pre + (size_t)n * Hd;
    const float* __restrict__ b1e  = b1 + (size_t)e * (Hd * Rr);
    const float* __restrict__ a2e  = a2 + (size_t)e * (Rr * Hd);

    float q[Rr];
#pragma unroll
    for (int r = 0; r < Rr; ++r) q[r] = 0.f;

#pragma unroll
    for (int i = 0; i < Hd / 256; ++i) {
        const int h = t + i * 256;
        const float4* bp = reinterpret_cast<const float4*>(b1e + (size_t)h * Rr);
        const float4 ba = bp[0];
        const float4 bb = bp[1];
        float d1 = t1l[0] * ba.x + t1l[1] * ba.y + t1l[2] * ba.z + t1l[3] * ba.w
                 + t1l[4] * bb.x + t1l[5] * bb.y + t1l[6] * bb.z + t1l[7] * bb.w;
        const float x  = hrow[h] + d1 * kScale;
        const float hv = x / (1.f + __expf(-x));   // silu
#pragma unroll
        for (int r = 0; r < Rr; ++r)
            q[r] = fmaf(hv, a2e[r * Hd + h], q[r]);
    }
#pragma unroll
    for (int r = 0; r < Rr; ++r) {
        float v = q[r];
#pragma unroll
        for (int off = 32; off > 0; off >>= 1)
            v += __shfl_down(v, off, 64);
        if (lane == 0) red[r][wave] = v;
    }
    __syncthreads();
    if (t < Rr)
        t2s[t] = red[t][0] + red[t][1] + red[t][2] + red[t][3];
    __syncthreads();

    float t2l[Rr];
#pragma unroll
    for (int r = 0; r < Rr; ++r) t2l[r] = t2s[r];

    // ---------- Phase 3: out[n,d] = out_pre[n,d] + sum_r t2[r] * b2[e,d,r] ----------
    const float* __restrict__ orow   = out_pre + (size_t)n * Zd;
    const float* __restrict__ b2e    = b2 + (size_t)e * (Zd * Rr);
    float*       __restrict__ outrow = out + (size_t)n * Zd;

#pragma unroll
    for (int i = 0; i < Zd / 256; ++i) {
        const int d = t + i * 256;
        const float4* bp = reinterpret_cast<const float4*>(b2e + (size_t)d * Rr);
        const float4 ba = bp[0];
        const float4 bb = bp[1];
        float d2 = t2l[0] * ba.x + t2l[1] * ba.y + t2l[2] * ba.z + t2l[3] * ba.w
                 + t2l[4] * bb.x + t2l[5] * bb.y + t2l[6] * bb.z + t2l[7] * bb.w;
        outrow[d] = orow[d] + d2 * kScale;
    }
}

extern "C" void kernel_launch(void* const* d_in, const int* in_sizes, int n_in,
                              void* d_out, int out_size, void* d_ws, size_t ws_size,
                              hipStream_t stream) {
    const float* z       = (const float*)d_in[0];
    const int*   a_idx   = (const int*)d_in[1];
    const float* h_pre   = (const float*)d_in[2];
    const float* out_pre = (const float*)d_in[3];
    const float* a1      = (const float*)d_in[4];
    const float* b1      = (const float*)d_in[5];
    const float* a2      = (const float*)d_in[6];
    const float* b2      = (const float*)d_in[7];
    float* out = (float*)d_out;

    const int N = in_sizes[1];  // a_idx count

    expert_lora_kernel<<<N, 256, 0, stream>>>(z, a_idx, h_pre, out_pre,
                                              a1, b1, a2, b2, out);
}

// Round 2
// 143.909 us; speedup vs baseline: 1.1733x; 1.1733x over previous
//
#include <hip/hip_runtime.h>

// ExpertLoRA: N=8192, Z=1024, H=2048, W=64, R=8, SCALE=1.0
// Strategy: bucket tokens by expert (tiny kernel), then main kernel processes
// 8 tokens of ONE expert per block (2 tokens per wave, in-wave reductions),
// with XCD-aware block swizzle so an expert's weights stay in one XCD's L2.

constexpr int Zd = 1024;
constexpr int Hd = 2048;
constexpr int Rr = 8;
constexpr int Wn = 64;
constexpr int TB = 8;            // tokens per block
constexpr float kScale = 1.0f;

// ws layout (ints): [0]=n_blocks, [16..16+N)=order, then int4 block table.

__global__ __launch_bounds__(256) void bucket_kernel(
    const int* __restrict__ a_idx, int N, int* __restrict__ ws)
{
    __shared__ int hist[Wn];
    __shared__ int cursor[Wn];
    const int t = threadIdx.x;
    if (t < Wn) hist[t] = 0;
    __syncthreads();
    for (int i = t; i < N; i += 256) atomicAdd(&hist[a_idx[i]], 1);
    __syncthreads();
    if (t == 0) {
        int4* btab = (int4*)(ws + 16 + N);
        int acc = 0, nb = 0;
        for (int e = 0; e < Wn; ++e) {
            cursor[e] = acc;
            const int c = hist[e];
            for (int s = 0; s < c; s += TB)
                btab[nb++] = make_int4(e, acc + s, min(TB, c - s), 0);
            acc += c;
        }
        ws[0] = nb;
    }
    __syncthreads();
    int* order = ws + 16;
    for (int i = t; i < N; i += 256) {
        const int pos = atomicAdd(&cursor[a_idx[i]], 1);
        order[pos] = i;
    }
}

__device__ __forceinline__ float wave_allreduce(float v) {
#pragma unroll
    for (int off = 1; off < 64; off <<= 1)
        v += __shfl_xor(v, off, 64);
    return v;
}

__device__ __forceinline__ float dot8(const float* t, float4 w0, float4 w1) {
    return fmaf(t[0], w0.x, fmaf(t[1], w0.y, fmaf(t[2], w0.z, fmaf(t[3], w0.w,
           fmaf(t[4], w1.x, fmaf(t[5], w1.y, fmaf(t[6], w1.z, t[7] * w1.w)))))));
}

__global__ __launch_bounds__(256) void lora_main(
    const float* __restrict__ z,        // [N, Z]
    const float* __restrict__ h_pre,    // [N, H]
    const float* __restrict__ out_pre,  // [N, Z]
    const float* __restrict__ a1,       // [W, R, Z]
    const float* __restrict__ b1,       // [W, H, R]
    const float* __restrict__ a2,       // [W, R, H]
    const float* __restrict__ b2,       // [W, Z, R]
    float* __restrict__ out,            // [N, Z]
    const int* __restrict__ ws, int N)
{
    // XCD-aware swizzle: gridDim.x is a multiple of 8, so each XCD gets a
    // contiguous run of logical blocks (consecutive experts share an L2).
    const int cpx = gridDim.x >> 3;
    const int lb  = (blockIdx.x & 7) * cpx + (blockIdx.x >> 3);
    if (lb >= ws[0]) return;

    const int4 desc = ((const int4*)(ws + 16 + N))[lb];
    const int e = desc.x, start = desc.y, cnt = desc.z;
    const int* order = ws + 16;

    const int wave = threadIdx.x >> 6;
    const int lane = threadIdx.x & 63;
    const int i0 = 2 * wave, i1 = 2 * wave + 1;
    const bool vA = (i0 < cnt), vB = (i1 < cnt);
    const int tA = order[start + (vA ? i0 : 0)];
    const int tB = order[start + (vB ? i1 : 0)];

    // ---------- Phase 1: t1[tok][r] = sum_d z[tok,d] * a1[e,r,d] ----------
    const float4* ZA = (const float4*)(z + (size_t)tA * Zd);
    const float4* ZB = (const float4*)(z + (size_t)tB * Zd);
    const float4* A1 = (const float4*)(a1 + (size_t)e * (Rr * Zd));

    float pA[Rr], pB[Rr];
#pragma unroll
    for (int r = 0; r < Rr; ++r) { pA[r] = 0.f; pB[r] = 0.f; }

#pragma unroll
    for (int i = 0; i < Zd / 256; ++i) {               // 4 iters
        const int c = lane + i * 64;                   // float4 index
        const float4 za = ZA[c];
        const float4 zb = ZB[c];
#pragma unroll
        for (int r = 0; r < Rr; ++r) {
            const float4 w = A1[r * (Zd / 4) + c];
            pA[r] = fmaf(za.x, w.x, fmaf(za.y, w.y, fmaf(za.z, w.z, fmaf(za.w, w.w, pA[r]))));
            pB[r] = fmaf(zb.x, w.x, fmaf(zb.y, w.y, fmaf(zb.z, w.z, fmaf(zb.w, w.w, pB[r]))));
        }
    }
    float t1A[Rr], t1B[Rr];
#pragma unroll
    for (int r = 0; r < Rr; ++r) {
        t1A[r] = wave_allreduce(pA[r]);
        t1B[r] = wave_allreduce(pB[r]);
    }

    // ---------- Phase 2: h = silu(h_pre + t1·b1^T); t2[r] = sum_h h*a2[e,r,h] ----------
    const float4* HA = (const float4*)(h_pre + (size_t)tA * Hd);
    const float4* HB = (const float4*)(h_pre + (size_t)tB * Hd);
    const float4* B1 = (const float4*)(b1 + (size_t)e * (Hd * Rr));   // row h = 2 float4
    const float4* A2 = (const float4*)(a2 + (size_t)e * (Rr * Hd));

    float qA[Rr], qB[Rr];
#pragma unroll
    for (int r = 0; r < Rr; ++r) { qA[r] = 0.f; qB[r] = 0.f; }

    for (int i = 0; i < Hd / 256; ++i) {               // 8 iters
        const int c = lane + i * 64;                   // float4 index over H
        const float4 ha = HA[c];
        const float4 hb = HB[c];
        float hva[4], hvb[4];
#pragma unroll
        for (int j = 0; j < 4; ++j) {
            const float4 w0 = B1[(4 * c + j) * 2 + 0];
            const float4 w1 = B1[(4 * c + j) * 2 + 1];
            const float xa = (&ha.x)[j] + dot8(t1A, w0, w1) * kScale;
            const float xb = (&hb.x)[j] + dot8(t1B, w0, w1) * kScale;
            hva[j] = xa / (1.f + __expf(-xa));
            hvb[j] = xb / (1.f + __expf(-xb));
        }
#pragma unroll
        for (int r = 0; r < Rr; ++r) {
            const float4 w = A2[r * (Hd / 4) + c];
            qA[r] = fmaf(hva[0], w.x, fmaf(hva[1], w.y, fmaf(hva[2], w.z, fmaf(hva[3], w.w, qA[r]))));
            qB[r] = fmaf(hvb[0], w.x, fmaf(hvb[1], w.y, fmaf(hvb[2], w.z, fmaf(hvb[3], w.w, qB[r]))));
        }
    }
    float t2A[Rr], t2B[Rr];
#pragma unroll
    for (int r = 0; r < Rr; ++r) {
        t2A[r] = wave_allreduce(qA[r]) * kScale;
        t2B[r] = wave_allreduce(qB[r]) * kScale;
    }

    // ---------- Phase 3: out[tok,d] = out_pre[tok,d] + t2·b2[e,d,:] ----------
    const float4* OA = (const float4*)(out_pre + (size_t)tA * Zd);
    const float4* OB = (const float4*)(out_pre + (size_t)tB * Zd);
    const float4* B2 = (const float4*)(b2 + (size_t)e * (Zd * Rr));   // row d = 2 float4
    float4* XA = (float4*)(out + (size_t)tA * Zd);
    float4* XB = (float4*)(out + (size_t)tB * Zd);

    for (int i = 0; i < Zd / 256; ++i) {               // 4 iters
        const int c = lane + i * 64;
        const float4 oa = OA[c];
        const float4 ob = OB[c];
        float4 ra, rb;
#pragma unroll
        for (int j = 0; j < 4; ++j) {
            const float4 w0 = B2[(4 * c + j) * 2 + 0];
            const float4 w1 = B2[(4 * c + j) * 2 + 1];
            (&ra.x)[j] = (&oa.x)[j] + dot8(t2A, w0, w1);
            (&rb.x)[j] = (&ob.x)[j] + dot8(t2B, w0, w1);
        }
        if (vA) XA[c] = ra;
        if (vB) XB[c] = rb;
    }
}

extern "C" void kernel_launch(void* const* d_in, const int* in_sizes, int n_in,
                              void* d_out, int out_size, void* d_ws, size_t ws_size,
                              hipStream_t stream) {
    const float* z       = (const float*)d_in[0];
    const int*   a_idx   = (const int*)d_in[1];
    const float* h_pre   = (const float*)d_in[2];
    const float* out_pre = (const float*)d_in[3];
    const float* a1      = (const float*)d_in[4];
    const float* b1      = (const float*)d_in[5];
    const float* a2      = (const float*)d_in[6];
    const float* b2      = (const float*)d_in[7];
    float* out = (float*)d_out;

    const int N = in_sizes[1];  // a_idx count

    bucket_kernel<<<1, 256, 0, stream>>>(a_idx, N, (int*)d_ws);

    int nwg = (N + TB - 1) / TB + Wn;   // worst-case block count incl. bucket tails
    nwg = (nwg + 7) & ~7;               // multiple of 8 for the XCD swizzle
    lora_main<<<nwg, 256, 0, stream>>>(z, h_pre, out_pre, a1, b1, a2, b2, out,
                                       (const int*)d_ws, N);
}

// Round 3
// 90.615 us; speedup vs baseline: 1.8634x; 1.5881x over previous
//
#include <hip/hip_runtime.h>

// ExpertLoRA: N=8192, Z=1024, H=2048, W=64, R=8, SCALE=1.0
// Round 2: 16 tokens/block (4 waves x 4 tokens), parallel bucket kernel,
// cheap silu (v_rcp + v_exp), XCD-aware swizzle kept.

constexpr int Zd = 1024;
constexpr int Hd = 2048;
constexpr int Rr = 8;
constexpr int Wn = 64;
constexpr int TB = 16;           // tokens per block
constexpr int TW = 4;            // tokens per wave
constexpr float kScale = 1.0f;

// ws layout (ints): [0]=n_blocks, [16..16+N)=order, then int4 block table.

__global__ __launch_bounds__(1024) void bucket_kernel(
    const int* __restrict__ a_idx, int N, int* __restrict__ ws)
{
    __shared__ int hist[Wn];
    __shared__ int cursor[Wn];
    const int t = threadIdx.x;
    if (t < Wn) hist[t] = 0;
    __syncthreads();
    for (int i = t; i < N; i += 1024) atomicAdd(&hist[a_idx[i]], 1);
    __syncthreads();

    if (t < Wn) {                       // wave 0 does both prefix scans
        const int c = hist[t];
        int scan = c;                   // inclusive scan of counts
#pragma unroll
        for (int off = 1; off < 64; off <<= 1) {
            const int v = __shfl_up(scan, off, 64);
            if (t >= off) scan += v;
        }
        const int base = scan - c;      // exclusive

        const int nb_e = (c + TB - 1) / TB;
        int bs = nb_e;                  // inclusive scan of block counts
#pragma unroll
        for (int off = 1; off < 64; off <<= 1) {
            const int v = __shfl_up(bs, off, 64);
            if (t >= off) bs += v;
        }
        const int bstart = bs - nb_e;
        if (t == Wn - 1) ws[0] = bs;    // total blocks
        cursor[t] = base;

        int4* btab = (int4*)(ws + 16 + N);
        for (int s = 0, k = 0; s < c; s += TB, ++k)
            btab[bstart + k] = make_int4(t, base + s, min(TB, c - s), 0);
    }
    __syncthreads();
    int* order = ws + 16;
    for (int i = t; i < N; i += 1024) {
        const int pos = atomicAdd(&cursor[a_idx[i]], 1);
        order[pos] = i;
    }
}

__device__ __forceinline__ float wave_allreduce(float v) {
#pragma unroll
    for (int off = 1; off < 64; off <<= 1)
        v += __shfl_xor(v, off, 64);
    return v;
}

__device__ __forceinline__ float dot8(const float* t, float4 w0, float4 w1) {
    return fmaf(t[0], w0.x, fmaf(t[1], w0.y, fmaf(t[2], w0.z, fmaf(t[3], w0.w,
           fmaf(t[4], w1.x, fmaf(t[5], w1.y, fmaf(t[6], w1.z, t[7] * w1.w)))))));
}

__device__ __forceinline__ float silu(float x) {
    // x * sigmoid(x); v_rcp_f32 is ~1e-6 rel err, fine vs 0.108 abs threshold
    return x * __builtin_amdgcn_rcpf(1.f + __expf(-x));
}

__global__ __launch_bounds__(256) void lora_main(
    const float* __restrict__ z,        // [N, Z]
    const float* __restrict__ h_pre,    // [N, H]
    const float* __restrict__ out_pre,  // [N, Z]
    const float* __restrict__ a1,       // [W, R, Z]
    const float* __restrict__ b1,       // [W, H, R]
    const float* __restrict__ a2,       // [W, R, H]
    const float* __restrict__ b2,       // [W, Z, R]
    float* __restrict__ out,            // [N, Z]
    const int* __restrict__ ws, int N)
{
    // XCD-aware swizzle (gridDim.x % 8 == 0): contiguous logical blocks
    // (= consecutive experts) land on one XCD's L2.
    const int cpx = gridDim.x >> 3;
    const int lb  = (blockIdx.x & 7) * cpx + (blockIdx.x >> 3);
    if (lb >= ws[0]) return;

    const int4 desc = ((const int4*)(ws + 16 + N))[lb];
    const int e = desc.x, start = desc.y, cnt = desc.z;
    const int* order = ws + 16;

    const int wave = threadIdx.x >> 6;
    const int lane = threadIdx.x & 63;

    bool val[TW];
    int  tok[TW];
#pragma unroll
    for (int k = 0; k < TW; ++k) {
        const int idx = wave * TW + k;
        val[k] = (idx < cnt);
        tok[k] = order[start + (val[k] ? idx : 0)];
    }

    // ---------- Phase 1: t1[k][r] = sum_d z[tok,d] * a1[e,r,d] ----------
    const float4* Zp[TW];
#pragma unroll
    for (int k = 0; k < TW; ++k) Zp[k] = (const float4*)(z + (size_t)tok[k] * Zd);
    const float4* A1 = (const float4*)(a1 + (size_t)e * (Rr * Zd));

    float p[TW][Rr];
#pragma unroll
    for (int k = 0; k < TW; ++k)
#pragma unroll
        for (int r = 0; r < Rr; ++r) p[k][r] = 0.f;

#pragma unroll
    for (int i = 0; i < Zd / 256; ++i) {               // 4 iters
        const int c = lane + i * 64;
        float4 zv[TW];
#pragma unroll
        for (int k = 0; k < TW; ++k) zv[k] = Zp[k][c];
#pragma unroll
        for (int r = 0; r < Rr; ++r) {
            const float4 w = A1[r * (Zd / 4) + c];
#pragma unroll
            for (int k = 0; k < TW; ++k)
                p[k][r] = fmaf(zv[k].x, w.x, fmaf(zv[k].y, w.y,
                          fmaf(zv[k].z, w.z, fmaf(zv[k].w, w.w, p[k][r]))));
        }
    }
    float t1[TW][Rr];
#pragma unroll
    for (int k = 0; k < TW; ++k)
#pragma unroll
        for (int r = 0; r < Rr; ++r) t1[k][r] = wave_allreduce(p[k][r]);

    // ---------- Phase 2: h = silu(h_pre + t1·b1^T); t2[r] = sum_h h*a2 ----------
    const float4* Hp[TW];
#pragma unroll
    for (int k = 0; k < TW; ++k) Hp[k] = (const float4*)(h_pre + (size_t)tok[k] * Hd);
    const float4* B1 = (const float4*)(b1 + (size_t)e * (Hd * Rr));
    const float4* A2 = (const float4*)(a2 + (size_t)e * (Rr * Hd));

    float q[TW][Rr];
#pragma unroll
    for (int k = 0; k < TW; ++k)
#pragma unroll
        for (int r = 0; r < Rr; ++r) q[k][r] = 0.f;

#pragma unroll 2
    for (int i = 0; i < Hd / 256; ++i) {               // 8 iters
        const int c = lane + i * 64;
        float4 hv[TW];
#pragma unroll
        for (int k = 0; k < TW; ++k) hv[k] = Hp[k][c];
        float s[TW][4];
#pragma unroll
        for (int j = 0; j < 4; ++j) {
            const float4 w0 = B1[(4 * c + j) * 2 + 0];
            const float4 w1 = B1[(4 * c + j) * 2 + 1];
#pragma unroll
            for (int k = 0; k < TW; ++k) {
                const float x = (&hv[k].x)[j] + dot8(t1[k], w0, w1) * kScale;
                s[k][j] = silu(x);
            }
        }
#pragma unroll
        for (int r = 0; r < Rr; ++r) {
            const float4 w = A2[r * (Hd / 4) + c];
#pragma unroll
            for (int k = 0; k < TW; ++k)
                q[k][r] = fmaf(s[k][0], w.x, fmaf(s[k][1], w.y,
                          fmaf(s[k][2], w.z, fmaf(s[k][3], w.w, q[k][r]))));
        }
    }
    float t2[TW][Rr];
#pragma unroll
    for (int k = 0; k < TW; ++k)
#pragma unroll
        for (int r = 0; r < Rr; ++r) t2[k][r] = wave_allreduce(q[k][r]) * kScale;

    // ---------- Phase 3: out = out_pre + t2·b2[e,d,:] ----------
    const float4* Op[TW];
    float4* Xp[TW];
#pragma unroll
    for (int k = 0; k < TW; ++k) {
        Op[k] = (const float4*)(out_pre + (size_t)tok[k] * Zd);
        Xp[k] = (float4*)(out + (size_t)tok[k] * Zd);
    }
    const float4* B2 = (const float4*)(b2 + (size_t)e * (Zd * Rr));

#pragma unroll 2
    for (int i = 0; i < Zd / 256; ++i) {               // 4 iters
        const int c = lane + i * 64;
        float4 ov[TW];
#pragma unroll
        for (int k = 0; k < TW; ++k) ov[k] = Op[k][c];
        float4 res[TW];
#pragma unroll
        for (int j = 0; j < 4; ++j) {
            const float4 w0 = B2[(4 * c + j) * 2 + 0];
            const float4 w1 = B2[(4 * c + j) * 2 + 1];
#pragma unroll
            for (int k = 0; k < TW; ++k)
                (&res[k].x)[j] = (&ov[k].x)[j] + dot8(t2[k], w0, w1);
        }
#pragma unroll
        for (int k = 0; k < TW; ++k)
            if (val[k]) Xp[k][c] = res[k];
    }
}

extern "C" void kernel_launch(void* const* d_in, const int* in_sizes, int n_in,
                              void* d_out, int out_size, void* d_ws, size_t ws_size,
                              hipStream_t stream) {
    const float* z       = (const float*)d_in[0];
    const int*   a_idx   = (const int*)d_in[1];
    const float* h_pre   = (const float*)d_in[2];
    const float* out_pre = (const float*)d_in[3];
    const float* a1      = (const float*)d_in[4];
    const float* b1      = (const float*)d_in[5];
    const float* a2      = (const float*)d_in[6];
    const float* b2      = (const float*)d_in[7];
    float* out = (float*)d_out;

    const int N = in_sizes[1];  // a_idx count

    bucket_kernel<<<1, 1024, 0, stream>>>(a_idx, N, (int*)d_ws);

    int nwg = N / TB + Wn;              // worst-case block count incl. tails
    nwg = (nwg + 7) & ~7;               // multiple of 8 for XCD swizzle
    lora_main<<<nwg, 256, 0, stream>>>(z, h_pre, out_pre, a1, b1, a2, b2, out,
                                       (const int*)d_ws, N);
}